// Round 1
// 144.350 us; speedup vs baseline: 1.0139x; 1.0139x over previous
//
#include <hip/hip_runtime.h>
#include <cstdint>

// CapsuleLayer dynamic routing: B=256, R=1152, C=10, O=16, I=8, 3 iters.
// fp32 in, fp32 out. Block = (c, 2 batches), NOW 768 threads (12 waves):
// thread-limit (2048/768) and LDS-limit (157KB/160KB) both give exactly
// 2 blocks/CU -> 24 waves/CU (75% occupancy, was 12 waves/37.5%).
// u for both batches lives in DYNAMIC LDS (76 KB), packed bf16 pairs,
// column-major with p-stride 1189 (=5 mod 32: conflict-free-ish both ways).
// W-slice read once per block, reused for 2 batches. Pass 0 fused into
// phase 1. Phase 2 parallelizes g across thread halves (waves 0-5 g=0,
// waves 6-11 g=1): halves each thread's butterfly/FMA chain.
// b_ij never stored: with b0=0, logit_k = u . (v0 + ... + v_{k-1}).
#define BB 256
#define RR 1152
#define CC 10
#define OO 16
#define II 8
#define NT 768
#define GG 2
#define NWAVE (NT / 64)    // 12
#define PSTR 1189          // p-row stride in words; 1189 % 32 == 5

__device__ __forceinline__ uint32_t f2bf(float f) {
    union { float f; uint32_t i; } v; v.f = f;
    return (v.i + 0x7fffu + ((v.i >> 16) & 1u)) >> 16;   // RNE
}
__device__ __forceinline__ void unpack2(uint32_t pk, float& lo, float& hi) {
    union { uint32_t i; float f; } a, b;
    a.i = pk << 16; b.i = pk & 0xffff0000u;
    lo = a.f; hi = b.f;
}
__device__ __forceinline__ float dot8(float4 a, float4 b, float4 xa, float4 xb) {
    float s = 0.f;
    s = fmaf(a.x, xa.x, s); s = fmaf(a.y, xa.y, s);
    s = fmaf(a.z, xa.z, s); s = fmaf(a.w, xa.w, s);
    s = fmaf(b.x, xb.x, s); s = fmaf(b.y, xb.y, s);
    s = fmaf(b.z, xb.z, s); s = fmaf(b.w, xb.w, s);
    return s;
}

__global__ __launch_bounds__(NT, 6)   // 6 waves/SIMD = 24 waves/CU -> VGPR <= 85
void k_caps(const float* __restrict__ x, const float* __restrict__ W,
            float* __restrict__ out) {
    extern __shared__ uint32_t u2[];          // [GG][8][PSTR] packed bf16 pairs
    __shared__ float part[NWAVE][17];         // wave index implies g (wv/6)
    __shared__ float p0s[NWAVE][8][GG][2];    // [wv][p][g][half]
    __shared__ float wsum[GG][OO];

    const int t = threadIdx.x;
    const int c  = blockIdx.x / (BB / GG);    // c-major: 128 blocks share W-slice
    const int b0 = (blockIdx.x % (BB / GG)) * GG;
    const int wv = t >> 6, l = t & 63;
    const int rg = t >> 3, p = t & 7;         // phase 1: 96 r-rows x 8 o-pairs

    uint32_t* uA = u2;                        // batch b0
    uint32_t* uB = u2 + 8 * PSTR;             // batch b0+1

    // ---- Phase 1: u[r,2p:2p+2] for both batches -> LDS; fused pass-0 sums ----
    float s00 = 0.f, s01 = 0.f, s10 = 0.f, s11 = 0.f;
#pragma unroll 2
    for (int it = 0; it < RR / 96; ++it) {    // 12 iterations
        const int r = it * 96 + rg;
        const float* wp = W + (((size_t)r * CC + c) * OO + 2 * p) * II;
        float4 a0 = *reinterpret_cast<const float4*>(wp);
        float4 a1 = *reinterpret_cast<const float4*>(wp + 4);
        float4 c0 = *reinterpret_cast<const float4*>(wp + 8);
        float4 c1 = *reinterpret_cast<const float4*>(wp + 12);
        const float* xp0 = x + ((size_t)b0 * RR + r) * II;
        const float* xp1 = xp0 + (size_t)RR * II;
        float4 x00 = *reinterpret_cast<const float4*>(xp0);
        float4 x01 = *reinterpret_cast<const float4*>(xp0 + 4);
        float4 x10 = *reinterpret_cast<const float4*>(xp1);
        float4 x11 = *reinterpret_cast<const float4*>(xp1 + 4);
        float lo0 = dot8(a0, a1, x00, x01);   // o=2p,   g=0
        float hi0 = dot8(c0, c1, x00, x01);   // o=2p+1, g=0
        float lo1 = dot8(a0, a1, x10, x11);   // o=2p,   g=1
        float hi1 = dot8(c0, c1, x10, x11);   // o=2p+1, g=1
        s00 += lo0; s01 += hi0; s10 += lo1; s11 += hi1;
        uA[p * PSTR + r] = f2bf(lo0) | (f2bf(hi0) << 16);
        uB[p * PSTR + r] = f2bf(lo1) | (f2bf(hi1) << 16);
    }
    // reduce pass-0 partials over the 8 r-lanes sharing p (masks 8,16,32)
#pragma unroll
    for (int m = 8; m < 64; m <<= 1) {
        s00 += __shfl_xor(s00, m); s01 += __shfl_xor(s01, m);
        s10 += __shfl_xor(s10, m); s11 += __shfl_xor(s11, m);
    }
    if (l < 8) {
        p0s[wv][l][0][0] = s00; p0s[wv][l][0][1] = s01;
        p0s[wv][l][1][0] = s10; p0s[wv][l][1][1] = s11;
    }
    __syncthreads();

    if (t < GG * OO) {   // g = t>>4, o = t&15 (wave 0)
        const int g = t >> 4, o = t & 15;
        float s = 0.f;
#pragma unroll
        for (int w = 0; w < NWAVE; ++w) s += p0s[w][o >> 1][g][o & 1];
        s *= (1.0f / RR);                     // softmax(0) = 1/R
        float ss = s * s;                     // squash over 16-lane o-group
        ss += __shfl_xor(ss, 1); ss += __shfl_xor(ss, 2);
        ss += __shfl_xor(ss, 4); ss += __shfl_xor(ss, 8);
        wsum[g][o] = s * (ss / ((1.0f + ss) * sqrtf(ss + 1e-7f)));  // v0
    }
    __syncthreads();

    // ---- Phase 2: passes 1 and 2 from LDS; g parallel across thread halves ----
    const int g2 = wv / 6;                    // waves 0-5: g=0, waves 6-11: g=1
    const int tt = t - g2 * 384;              // [0,384) within the g-half
    const uint32_t* ug = g2 ? uB : uA;

    for (int pass = 1; pass < 3; ++pass) {
        float wreg[OO];
#pragma unroll
        for (int k = 0; k < OO; ++k) wreg[k] = wsum[g2][k];  // broadcast
        float num[OO];
#pragma unroll
        for (int k = 0; k < OO; ++k) num[k] = 0.f;
        float den = 0.f;

#pragma unroll
        for (int k = 0; k < 3; ++k) {
            const int r = tt + 384 * k;
            float ur[OO];
#pragma unroll
            for (int pp = 0; pp < 8; ++pp)  // bank = (5pp + r)%32: 2-way, free
                unpack2(ug[pp * PSTR + r], ur[2 * pp], ur[2 * pp + 1]);
            float lg = 0.f;
#pragma unroll
            for (int k2 = 0; k2 < OO; ++k2) lg = fmaf(ur[k2], wreg[k2], lg);
            float e = __expf(lg);   // |logit| <~ 40: fp32-safe
            den += e;
#pragma unroll
            for (int k2 = 0; k2 < OO; ++k2) num[k2] = fmaf(e, ur[k2], num[k2]);
        }

#pragma unroll
        for (int m = 1; m < 64; m <<= 1) {
#pragma unroll
            for (int k = 0; k < OO; ++k) num[k] += __shfl_xor(num[k], m);
            den += __shfl_xor(den, m);
        }
        if (l == 0) {
#pragma unroll
            for (int k = 0; k < OO; ++k) part[wv][k] = num[k];
            part[wv][16] = den;
        }
        __syncthreads();

        if (t < GG * OO) {
            const int g = t >> 4, o = t & 15;
            float nf = 0.f, df = 0.f;
#pragma unroll
            for (int w = 0; w < 6; ++w) {
                nf += part[6 * g + w][o];
                df += part[6 * g + w][16];
            }
            float s = nf / df;
            float ss = s * s;
            ss += __shfl_xor(ss, 1); ss += __shfl_xor(ss, 2);
            ss += __shfl_xor(ss, 4); ss += __shfl_xor(ss, 8);
            float v = s * (ss / ((1.0f + ss) * sqrtf(ss + 1e-7f)));
            if (pass == 2)
                out[((size_t)(b0 + g) * CC + c) * OO + o] = v;
            else
                wsum[g][o] += v;
        }
        __syncthreads();
    }
}

extern "C" void kernel_launch(void* const* d_in, const int* in_sizes, int n_in,
                              void* d_out, int out_size, void* d_ws, size_t ws_size,
                              hipStream_t stream) {
    const float* x = (const float*)d_in[0];  // (B,R,I) fp32
    const float* W = (const float*)d_in[1];  // (R,C,O,I) fp32
    if (n_in >= 2 && in_sizes[0] == RR * CC * OO * II &&
        in_sizes[1] == BB * RR * II) {
        const float* tmp = x; x = W; W = tmp;
    }
    float* out = (float*)d_out;              // (B,1,C,O,1) fp32

    const size_t dyn_lds = (size_t)GG * 8 * PSTR * 4;   // 76,096 B
    k_caps<<<CC * (BB / GG), NT, dyn_lds, stream>>>(x, W, out);
}

// Round 2
// 130.019 us; speedup vs baseline: 1.1256x; 1.1102x over previous
//
#include <hip/hip_runtime.h>
#include <cstdint>

// CapsuleLayer dynamic routing: B=256, R=1152, C=10, O=16, I=8, 3 iters.
// Round 2: phase-1 W loads re-sliced for per-instruction coalescing.
// OLD: lane p read its own o-pair (4x16B at 64B lane-stride) -> each VMEM
// instr touched 64 distinct 64B lines (TA request-rate wall, ~290 lookups
// per wave-iter; occupancy-insensitive, VALU 29%, HBM 3.7%).
// NEW: lane p, piece j reads floats [j*32+p*4) -> 8 lanes contiguous 128B
// -> 16 lookups/instr (4x fewer). Lane holds half-dots of o=4j+(p>>1);
// DPP quad_perm xor-1 add completes the dot (VALU pipe, not LDS);
// DPP xor-2 + v_perm_b32 repacks bf16 pairs for the UNCHANGED LDS layout.
// x: each lane loads only its i-half (halves x lookups too).
// Phase 2 (passes 1,2 from LDS, g split across wave halves) unchanged.
#define BB 256
#define RR 1152
#define CC 10
#define OO 16
#define II 8
#define NT 768
#define GG 2
#define NWAVE (NT / 64)    // 12
#define PSTR 1189          // p-row stride in words; 1189 % 32 == 5

__device__ __forceinline__ uint32_t f2bf(float f) {
    union { float f; uint32_t i; } v; v.f = f;
    return (v.i + 0x7fffu + ((v.i >> 16) & 1u)) >> 16;   // RNE
}
__device__ __forceinline__ void unpack2(uint32_t pk, float& lo, float& hi) {
    union { uint32_t i; float f; } a, b;
    a.i = pk << 16; b.i = pk & 0xffff0000u;
    lo = a.f; hi = b.f;
}
__device__ __forceinline__ float dot4(float4 a, float4 b) {
    float s = a.x * b.x;
    s = fmaf(a.y, b.y, s); s = fmaf(a.z, b.z, s); s = fmaf(a.w, b.w, s);
    return s;
}
// v + (value from lane l^1), via DPP quad_perm [1,0,3,2] — VALU pipe, free
__device__ __forceinline__ float qpadd1(float v) {
    int o = __builtin_amdgcn_mov_dpp(__float_as_int(v), 0xB1, 0xF, 0xF, true);
    return v + __int_as_float(o);
}
// value from lane l^2, via DPP quad_perm [2,3,0,1]
__device__ __forceinline__ uint32_t dppx2(uint32_t v) {
    return (uint32_t)__builtin_amdgcn_mov_dpp((int)v, 0x4E, 0xF, 0xF, true);
}

__global__ __launch_bounds__(NT, 6)   // 6 waves/SIMD = 24 waves/CU
void k_caps(const float* __restrict__ x, const float* __restrict__ W,
            float* __restrict__ out) {
    extern __shared__ uint32_t u2[];          // [GG][8][PSTR] packed bf16 pairs
    __shared__ float part[NWAVE][17];         // wave index implies g (wv/6)
    __shared__ float p0s[NWAVE][8][4][GG];    // [wv][lane 2q][j][g]
    __shared__ float wsum[GG][OO];

    const int t = threadIdx.x;
    const int c  = blockIdx.x / (BB / GG);    // c-major: 128 blocks share W-slice
    const int b0 = (blockIdx.x % (BB / GG)) * GG;
    const int wv = t >> 6, l = t & 63;
    const int rg = t >> 3, p = t & 7;         // phase 1: 96 r-rows x 8 lanes

    uint32_t* uA = u2;                        // batch b0
    uint32_t* uB = u2 + 8 * PSTR;             // batch b0+1

    // per-thread constants for the repack/store
    const int pw = 2 * (p & 3) + (p >> 2);    // opair this lane writes (bijective)
    const uint32_t psel = (p & 2) ? 0x01000504u : 0x05040100u;  // v_perm selector
    uint32_t* wrA = uA + pw * PSTR;
    uint32_t* wrB = uB + pw * PSTR;

    // ---- Phase 1: u -> LDS (coalesced W reads); fused pass-0 sums ----
    float s00 = 0.f, s01 = 0.f, s02 = 0.f, s03 = 0.f;
    float s10 = 0.f, s11 = 0.f, s12 = 0.f, s13 = 0.f;
#pragma unroll 2
    for (int it = 0; it < RR / 96; ++it) {    // 12 iterations
        const int r = it * 96 + rg;
        // W row (128 floats, 512B contiguous): piece j = floats [j*32+p*4, +4)
        const float* wrow = W + ((size_t)r * CC + c) * (OO * II) + p * 4;
        float4 w0 = *reinterpret_cast<const float4*>(wrow);
        float4 w1 = *reinterpret_cast<const float4*>(wrow + 32);
        float4 w2 = *reinterpret_cast<const float4*>(wrow + 64);
        float4 w3 = *reinterpret_cast<const float4*>(wrow + 96);
        // x: lane loads only its i-half (p&1)
        const float* xp = x + ((size_t)b0 * RR + r) * II + (p & 1) * 4;
        float4 xh0 = *reinterpret_cast<const float4*>(xp);
        float4 xh1 = *reinterpret_cast<const float4*>(xp + (size_t)RR * II);

        // ---- g = 0 ----  d[j] = full dot for o = 4j + (p>>1)
        float d0 = qpadd1(dot4(w0, xh0));
        float d1 = qpadd1(dot4(w1, xh0));
        float d2 = qpadd1(dot4(w2, xh0));
        float d3 = qpadd1(dot4(w3, xh0));
        s00 += d0; s01 += d1; s02 += d2; s03 += d3;
        {
            uint32_t m0 = f2bf(d0), m1 = f2bf(d1), m2 = f2bf(d2), m3 = f2bf(d3);
            uint32_t q0 = __builtin_amdgcn_perm(dppx2(m0), m0, psel);
            uint32_t q1 = __builtin_amdgcn_perm(dppx2(m1), m1, psel);
            uint32_t q2 = __builtin_amdgcn_perm(dppx2(m2), m2, psel);
            uint32_t q3 = __builtin_amdgcn_perm(dppx2(m3), m3, psel);
            uint32_t sa = (p & 2) ? ((p & 1) ? q3 : q2) : ((p & 1) ? q1 : q0);
            wrA[r] = sa;                      // bank = (5*pw + r)%32: 2-way, free
        }
        // ---- g = 1 ----
        float e0 = qpadd1(dot4(w0, xh1));
        float e1 = qpadd1(dot4(w1, xh1));
        float e2 = qpadd1(dot4(w2, xh1));
        float e3 = qpadd1(dot4(w3, xh1));
        s10 += e0; s11 += e1; s12 += e2; s13 += e3;
        {
            uint32_t m0 = f2bf(e0), m1 = f2bf(e1), m2 = f2bf(e2), m3 = f2bf(e3);
            uint32_t q0 = __builtin_amdgcn_perm(dppx2(m0), m0, psel);
            uint32_t q1 = __builtin_amdgcn_perm(dppx2(m1), m1, psel);
            uint32_t q2 = __builtin_amdgcn_perm(dppx2(m2), m2, psel);
            uint32_t q3 = __builtin_amdgcn_perm(dppx2(m3), m3, psel);
            uint32_t sa = (p & 2) ? ((p & 1) ? q3 : q2) : ((p & 1) ? q1 : q0);
            wrB[r] = sa;
        }
    }
    // reduce pass-0 partials over the 8 r-groups of the wave (masks 8,16,32)
#pragma unroll
    for (int m = 8; m < 64; m <<= 1) {
        s00 += __shfl_xor(s00, m); s01 += __shfl_xor(s01, m);
        s02 += __shfl_xor(s02, m); s03 += __shfl_xor(s03, m);
        s10 += __shfl_xor(s10, m); s11 += __shfl_xor(s11, m);
        s12 += __shfl_xor(s12, m); s13 += __shfl_xor(s13, m);
    }
    if (l < 8) {          // lane l holds o = 4j + (l>>1); dup pairs harmless
        p0s[wv][l][0][0] = s00; p0s[wv][l][1][0] = s01;
        p0s[wv][l][2][0] = s02; p0s[wv][l][3][0] = s03;
        p0s[wv][l][0][1] = s10; p0s[wv][l][1][1] = s11;
        p0s[wv][l][2][1] = s12; p0s[wv][l][3][1] = s13;
    }
    __syncthreads();

    if (t < GG * OO) {   // g = t>>4, o = t&15 (wave 0)
        const int g = t >> 4, o = t & 15;
        float s = 0.f;
#pragma unroll
        for (int w = 0; w < NWAVE; ++w) s += p0s[w][2 * (o & 3)][o >> 2][g];
        s *= (1.0f / RR);                     // softmax(0) = 1/R
        float ss = s * s;                     // squash over 16-lane o-group
        ss += __shfl_xor(ss, 1); ss += __shfl_xor(ss, 2);
        ss += __shfl_xor(ss, 4); ss += __shfl_xor(ss, 8);
        wsum[g][o] = s * (ss / ((1.0f + ss) * sqrtf(ss + 1e-7f)));  // v0
    }
    __syncthreads();

    // ---- Phase 2: passes 1 and 2 from LDS; g parallel across thread halves ----
    const int g2 = wv / 6;                    // waves 0-5: g=0, waves 6-11: g=1
    const int tt = t - g2 * 384;              // [0,384) within the g-half
    const uint32_t* ug = g2 ? uB : uA;

    for (int pass = 1; pass < 3; ++pass) {
        float wreg[OO];
#pragma unroll
        for (int k = 0; k < OO; ++k) wreg[k] = wsum[g2][k];  // broadcast
        float num[OO];
#pragma unroll
        for (int k = 0; k < OO; ++k) num[k] = 0.f;
        float den = 0.f;

#pragma unroll
        for (int k = 0; k < 3; ++k) {
            const int r = tt + 384 * k;
            float ur[OO];
#pragma unroll
            for (int pp = 0; pp < 8; ++pp)  // bank = (5pp + r)%32: 2-way, free
                unpack2(ug[pp * PSTR + r], ur[2 * pp], ur[2 * pp + 1]);
            float lg = 0.f;
#pragma unroll
            for (int k2 = 0; k2 < OO; ++k2) lg = fmaf(ur[k2], wreg[k2], lg);
            float e = __expf(lg);   // |logit| <~ 40: fp32-safe
            den += e;
#pragma unroll
            for (int k2 = 0; k2 < OO; ++k2) num[k2] = fmaf(e, ur[k2], num[k2]);
        }

#pragma unroll
        for (int m = 1; m < 64; m <<= 1) {
#pragma unroll
            for (int k = 0; k < OO; ++k) num[k] += __shfl_xor(num[k], m);
            den += __shfl_xor(den, m);
        }
        if (l == 0) {
#pragma unroll
            for (int k = 0; k < OO; ++k) part[wv][k] = num[k];
            part[wv][16] = den;
        }
        __syncthreads();

        if (t < GG * OO) {
            const int g = t >> 4, o = t & 15;
            float nf = 0.f, df = 0.f;
#pragma unroll
            for (int w = 0; w < 6; ++w) {
                nf += part[6 * g + w][o];
                df += part[6 * g + w][16];
            }
            float s = nf / df;
            float ss = s * s;
            ss += __shfl_xor(ss, 1); ss += __shfl_xor(ss, 2);
            ss += __shfl_xor(ss, 4); ss += __shfl_xor(ss, 8);
            float v = s * (ss / ((1.0f + ss) * sqrtf(ss + 1e-7f)));
            if (pass == 2)
                out[((size_t)(b0 + g) * CC + c) * OO + o] = v;
            else
                wsum[g][o] += v;
        }
        __syncthreads();
    }
}

extern "C" void kernel_launch(void* const* d_in, const int* in_sizes, int n_in,
                              void* d_out, int out_size, void* d_ws, size_t ws_size,
                              hipStream_t stream) {
    const float* x = (const float*)d_in[0];  // (B,R,I) fp32
    const float* W = (const float*)d_in[1];  // (R,C,O,I) fp32
    if (n_in >= 2 && in_sizes[0] == RR * CC * OO * II &&
        in_sizes[1] == BB * RR * II) {
        const float* tmp = x; x = W; W = tmp;
    }
    float* out = (float*)d_out;              // (B,1,C,O,1) fp32

    const size_t dyn_lds = (size_t)GG * 8 * PSTR * 4;   // 76,096 B
    k_caps<<<CC * (BB / GG), NT, dyn_lds, stream>>>(x, W, out);
}

// Round 4
// 109.744 us; speedup vs baseline: 1.3336x; 1.1848x over previous
//
#include <hip/hip_runtime.h>
#include <cstdint>

// CapsuleLayer dynamic routing: B=256, R=1152, C=10, O=16, I=8, 3 iters.
// Round 4 = round 3 with the den-scale bug fixed.
//  * Phase 2 lane-QUAD ownership: each 4-lane quad owns one r; lane q=l&3
//    reads LDS rows q and q+4 (4 o's), logit completed with 2 DPP
//    quad-perm adds (VALU pipe). Cross-lane reduce = masks {4,8,16,32}
//    on 5 values (20 shuffles/pass vs 102 in round 2).
//    NOTE: the reduce sums the 16 same-q lanes, which hold DISTINCT r's,
//    so den enters exactly once per r -> NO 0.25 factor (round-3 bug:
//    den*0.25 made softmax denom 4x small -> absmax 0.43).
//  * Phase 1 packs with v_cvt_pk_bf16_f32 (1 op) on (own, DPP-partner):
//    p&2 lanes produce swapped halves -> LDS rows 4-7 hold (odd,even);
//    phase-2 reader statically swap-unpacks rows >=4. Same bf16 grid.
// W loads per-instruction coalesced (round-2 fix: 16 lines/instr).
// 768 threads, 2 blocks/CU (LDS 76KB), g split across wave halves.
#define BB 256
#define RR 1152
#define CC 10
#define OO 16
#define II 8
#define NT 768
#define GG 2
#define NWAVE (NT / 64)    // 12
#define PSTR 1189          // p-row stride in words; 1189 % 32 == 5

__device__ __forceinline__ void unpack2(uint32_t pk, float& lo, float& hi) {
    union { uint32_t i; float f; } a, b;
    a.i = pk << 16; b.i = pk & 0xffff0000u;
    lo = a.f; hi = b.f;
}
__device__ __forceinline__ float dot4(float4 a, float4 b) {
    float s = a.x * b.x;
    s = fmaf(a.y, b.y, s); s = fmaf(a.z, b.z, s); s = fmaf(a.w, b.w, s);
    return s;
}
// v + (value from lane l^1), DPP quad_perm [1,0,3,2] — VALU pipe
__device__ __forceinline__ float qpadd1(float v) {
    int o = __builtin_amdgcn_mov_dpp(__float_as_int(v), 0xB1, 0xF, 0xF, true);
    return v + __int_as_float(o);
}
// v + (value from lane l^2), DPP quad_perm [2,3,0,1]
__device__ __forceinline__ float qpadd2(float v) {
    int o = __builtin_amdgcn_mov_dpp(__float_as_int(v), 0x4E, 0xF, 0xF, true);
    return v + __int_as_float(o);
}
// value from lane l^2 (float), DPP quad_perm [2,3,0,1]
__device__ __forceinline__ float dppx2f(float v) {
    return __int_as_float(__builtin_amdgcn_mov_dpp(__float_as_int(v), 0x4E, 0xF, 0xF, true));
}
// packed bf16 pair from two f32 (hardware RNE), one instruction
__device__ __forceinline__ uint32_t cvtpk(float lo, float hi) {
    uint32_t r;
    asm("v_cvt_pk_bf16_f32 %0, %1, %2" : "=v"(r) : "v"(lo), "v"(hi));
    return r;
}

__global__ __launch_bounds__(NT, 6)   // 6 waves/SIMD = 24 waves/CU
void k_caps(const float* __restrict__ x, const float* __restrict__ W,
            float* __restrict__ out) {
    extern __shared__ uint32_t u2[];          // [GG][8][PSTR] packed bf16 pairs
    __shared__ float part[NWAVE][17];         // wave index implies g (wv/6)
    __shared__ float p0s[NWAVE][8][4][GG];    // [wv][lane 2q][j][g]
    __shared__ float wsum[GG][OO];

    const int t = threadIdx.x;
    const int c  = blockIdx.x / (BB / GG);    // c-major: 128 blocks share W-slice
    const int b0 = (blockIdx.x % (BB / GG)) * GG;
    const int wv = t >> 6, l = t & 63;
    const int rg = t >> 3, p = t & 7;         // phase 1: 96 r-rows x 8 lanes

    uint32_t* uA = u2;                        // batch b0
    uint32_t* uB = u2 + 8 * PSTR;             // batch b0+1

    const int pw = 2 * (p & 3) + (p >> 2);    // row this lane writes (bijective)
    uint32_t* wrA = uA + pw * PSTR;
    uint32_t* wrB = uB + pw * PSTR;

    // ---- Phase 1: u -> LDS (coalesced W reads); fused pass-0 sums ----
    float s00 = 0.f, s01 = 0.f, s02 = 0.f, s03 = 0.f;
    float s10 = 0.f, s11 = 0.f, s12 = 0.f, s13 = 0.f;
#pragma unroll 2
    for (int it = 0; it < RR / 96; ++it) {    // 12 iterations
        const int r = it * 96 + rg;
        // W row (128 floats, 512B contiguous): piece j = floats [j*32+p*4, +4)
        const float* wrow = W + ((size_t)r * CC + c) * (OO * II) + p * 4;
        float4 w0 = *reinterpret_cast<const float4*>(wrow);
        float4 w1 = *reinterpret_cast<const float4*>(wrow + 32);
        float4 w2 = *reinterpret_cast<const float4*>(wrow + 64);
        float4 w3 = *reinterpret_cast<const float4*>(wrow + 96);
        // x: lane loads only its i-half (p&1)
        const float* xp = x + ((size_t)b0 * RR + r) * II + (p & 1) * 4;
        float4 xh0 = *reinterpret_cast<const float4*>(xp);
        float4 xh1 = *reinterpret_cast<const float4*>(xp + (size_t)RR * II);

        // ---- g = 0 ----  d[j] = full dot for o = 4j + (p>>1)
        float d0 = qpadd1(dot4(w0, xh0));
        float d1 = qpadd1(dot4(w1, xh0));
        float d2 = qpadd1(dot4(w2, xh0));
        float d3 = qpadd1(dot4(w3, xh0));
        s00 += d0; s01 += d1; s02 += d2; s03 += d3;
        {
            uint32_t q0 = cvtpk(d0, dppx2f(d0));   // (own, partner)
            uint32_t q1 = cvtpk(d1, dppx2f(d1));
            uint32_t q2 = cvtpk(d2, dppx2f(d2));
            uint32_t q3 = cvtpk(d3, dppx2f(d3));
            uint32_t sa = (p & 2) ? ((p & 1) ? q3 : q2) : ((p & 1) ? q1 : q0);
            wrA[r] = sa;                      // bank = (5*pw + r)%32: 2-way, free
        }
        // ---- g = 1 ----
        float e0 = qpadd1(dot4(w0, xh1));
        float e1 = qpadd1(dot4(w1, xh1));
        float e2 = qpadd1(dot4(w2, xh1));
        float e3 = qpadd1(dot4(w3, xh1));
        s10 += e0; s11 += e1; s12 += e2; s13 += e3;
        {
            uint32_t q0 = cvtpk(e0, dppx2f(e0));
            uint32_t q1 = cvtpk(e1, dppx2f(e1));
            uint32_t q2 = cvtpk(e2, dppx2f(e2));
            uint32_t q3 = cvtpk(e3, dppx2f(e3));
            uint32_t sa = (p & 2) ? ((p & 1) ? q3 : q2) : ((p & 1) ? q1 : q0);
            wrB[r] = sa;
        }
    }
    // reduce pass-0 partials over the 8 r-groups of the wave (masks 8,16,32)
#pragma unroll
    for (int m = 8; m < 64; m <<= 1) {
        s00 += __shfl_xor(s00, m); s01 += __shfl_xor(s01, m);
        s02 += __shfl_xor(s02, m); s03 += __shfl_xor(s03, m);
        s10 += __shfl_xor(s10, m); s11 += __shfl_xor(s11, m);
        s12 += __shfl_xor(s12, m); s13 += __shfl_xor(s13, m);
    }
    if (l < 8) {          // lane l holds o = 4j + (l>>1); dup pairs harmless
        p0s[wv][l][0][0] = s00; p0s[wv][l][1][0] = s01;
        p0s[wv][l][2][0] = s02; p0s[wv][l][3][0] = s03;
        p0s[wv][l][0][1] = s10; p0s[wv][l][1][1] = s11;
        p0s[wv][l][2][1] = s12; p0s[wv][l][3][1] = s13;
    }
    __syncthreads();

    if (t < GG * OO) {   // g = t>>4, o = t&15 (wave 0)
        const int g = t >> 4, o = t & 15;
        float s = 0.f;
#pragma unroll
        for (int w = 0; w < NWAVE; ++w) s += p0s[w][2 * (o & 3)][o >> 2][g];
        s *= (1.0f / RR);                     // softmax(0) = 1/R
        float ss = s * s;                     // squash over 16-lane o-group
        ss += __shfl_xor(ss, 1); ss += __shfl_xor(ss, 2);
        ss += __shfl_xor(ss, 4); ss += __shfl_xor(ss, 8);
        wsum[g][o] = s * (ss / ((1.0f + ss) * sqrtf(ss + 1e-7f)));  // v0
    }
    __syncthreads();

    // ---- Phase 2: passes 1 and 2 from LDS; lane-quad owns one r ----
    const int g2 = wv / 6;                    // waves 0-5: g=0, waves 6-11: g=1
    const int wv6 = wv - g2 * 6;              // wave within the g-half
    const uint32_t* ug = g2 ? uB : uA;
    const int q = l & 3;                      // owns o in {2q,2q+1,2q+8,2q+9}
    const int rl = l >> 2;                    // 0..15
    const uint32_t* rp0 = ug + (size_t)q * PSTR;        // row q   (normal)
    const uint32_t* rp1 = ug + (size_t)(q + 4) * PSTR;  // row q+4 (swapped)
    const int rbase = wv6 * 16 + rl;

    for (int pass = 1; pass < 3; ++pass) {
        const float wq0 = wsum[g2][2 * q];
        const float wq1 = wsum[g2][2 * q + 1];
        const float wq2 = wsum[g2][2 * q + 8];
        const float wq3 = wsum[g2][2 * q + 9];
        float n0 = 0.f, n1 = 0.f, n2 = 0.f, n3 = 0.f, den = 0.f;

#pragma unroll
        for (int it2 = 0; it2 < 12; ++it2) {
            const int r = it2 * 96 + rbase;
            uint32_t pa = rp0[r];             // bank (5q+r)%32: ~2-3 way
            uint32_t pb = rp1[r];
            float u0, u1, u2, u3;
            unpack2(pa, u0, u1);              // row q: (2q, 2q+1)
            unpack2(pb, u3, u2);              // row q+4 swapped: (2q+9, 2q+8)
            float lg = fmaf(u1, wq1, u0 * wq0);
            lg = fmaf(u2, wq2, lg);
            lg = fmaf(u3, wq3, lg);
            lg = qpadd1(lg);                  // + lane^1 (quad partial)
            lg = qpadd2(lg);                  // + lane^2: full 16-o logit
            float e = __expf(lg);             // |logit| <~ 40: fp32-safe
            den += e;                         // same-q lanes hold distinct r's
            n0 = fmaf(e, u0, n0); n1 = fmaf(e, u1, n1);
            n2 = fmaf(e, u2, n2); n3 = fmaf(e, u3, n3);
        }

#pragma unroll
        for (int m = 4; m < 64; m <<= 1) {
            n0 += __shfl_xor(n0, m); n1 += __shfl_xor(n1, m);
            n2 += __shfl_xor(n2, m); n3 += __shfl_xor(n3, m);
            den += __shfl_xor(den, m);
        }
        if (l < 4) {                          // lane l == q
            part[wv][2 * l]     = n0;
            part[wv][2 * l + 1] = n1;
            part[wv][2 * l + 8] = n2;
            part[wv][2 * l + 9] = n3;
            if (l == 0) part[wv][16] = den;   // each r counted exactly once
        }
        __syncthreads();

        if (t < GG * OO) {
            const int g = t >> 4, o = t & 15;
            float nf = 0.f, df = 0.f;
#pragma unroll
            for (int w = 0; w < 6; ++w) {
                nf += part[6 * g + w][o];
                df += part[6 * g + w][16];
            }
            float s = nf / df;
            float ss = s * s;
            ss += __shfl_xor(ss, 1); ss += __shfl_xor(ss, 2);
            ss += __shfl_xor(ss, 4); ss += __shfl_xor(ss, 8);
            float v = s * (ss / ((1.0f + ss) * sqrtf(ss + 1e-7f)));
            if (pass == 2)
                out[((size_t)(b0 + g) * CC + c) * OO + o] = v;
            else
                wsum[g][o] += v;
        }
        __syncthreads();
    }
}

extern "C" void kernel_launch(void* const* d_in, const int* in_sizes, int n_in,
                              void* d_out, int out_size, void* d_ws, size_t ws_size,
                              hipStream_t stream) {
    const float* x = (const float*)d_in[0];  // (B,R,I) fp32
    const float* W = (const float*)d_in[1];  // (R,C,O,I) fp32
    if (n_in >= 2 && in_sizes[0] == RR * CC * OO * II &&
        in_sizes[1] == BB * RR * II) {
        const float* tmp = x; x = W; W = tmp;
    }
    float* out = (float*)d_out;              // (B,1,C,O,1) fp32

    const size_t dyn_lds = (size_t)GG * 8 * PSTR * 4;   // 76,096 B
    k_caps<<<CC * (BB / GG), NT, dyn_lds, stream>>>(x, W, out);
}

// Round 6
// 107.939 us; speedup vs baseline: 1.3559x; 1.0167x over previous
//
#include <hip/hip_runtime.h>
#include <cstdint>

// CapsuleLayer dynamic routing: B=256, R=1152, C=10, O=16, I=8, 3 iters.
// Round 6 = round 5 resubmitted (container infra failure; kernel never ran).
//  * u layout [g][r][8] words (NO padding, 73.7KB): word r*8+pos,
//    pos = (p>>1)+((p&1)<<2) places o-pair row q at word 2q and row q+4
//    at 2q+1. Phase-1 write bank = (8rg+pos)%32 -> exact 2-way (free).
//    Phase-2 reads rows q,q+4 as ONE ds_read_b64 (uint2) -> 1 instr,
//    structural-minimum banking. (Round-4 PSTR=1189 p-major was 4-way
//    conflicted on phase-2 reads: SQ_LDS_BANK_CONFLICT 2.27M.)
//  * Phase-2 inner uses float2v packed pairs P0=(u0,u2), P1=(u1,u3):
//    logit = pk_fma(P0,WQA, P1*WQB) + hadd; num = 2 pk_fma. Lowered to
//    v_pk_fma_f32 (gfx90a+); written as elementwise C for compile safety.
//  * Phase-1 dots stay scalar (pk pairs there would be mov-bound).
// 768 threads, 2 blocks/CU, g split across wave halves in phase 2.
#define BB 256
#define RR 1152
#define CC 10
#define OO 16
#define II 8
#define NT 768
#define GG 2
#define NWAVE (NT / 64)    // 12

typedef float float2v __attribute__((ext_vector_type(2)));

__device__ __forceinline__ float bflo(uint32_t pk) {
    union { uint32_t i; float f; } a; a.i = pk << 16; return a.f;
}
__device__ __forceinline__ float bfhi(uint32_t pk) {
    union { uint32_t i; float f; } a; a.i = pk & 0xffff0000u; return a.f;
}
__device__ __forceinline__ float dot4(float4 a, float4 b) {
    float s = a.x * b.x;
    s = fmaf(a.y, b.y, s); s = fmaf(a.z, b.z, s); s = fmaf(a.w, b.w, s);
    return s;
}
// v + (value from lane l^1), DPP quad_perm [1,0,3,2] — VALU pipe
__device__ __forceinline__ float qpadd1(float v) {
    int o = __builtin_amdgcn_mov_dpp(__float_as_int(v), 0xB1, 0xF, 0xF, true);
    return v + __int_as_float(o);
}
// v + (value from lane l^2), DPP quad_perm [2,3,0,1]
__device__ __forceinline__ float qpadd2(float v) {
    int o = __builtin_amdgcn_mov_dpp(__float_as_int(v), 0x4E, 0xF, 0xF, true);
    return v + __int_as_float(o);
}
// value from lane l^2 (float), DPP quad_perm [2,3,0,1]
__device__ __forceinline__ float dppx2f(float v) {
    return __int_as_float(__builtin_amdgcn_mov_dpp(__float_as_int(v), 0x4E, 0xF, 0xF, true));
}
// packed bf16 pair from two f32 (hardware RNE), one instruction
__device__ __forceinline__ uint32_t cvtpk(float lo, float hi) {
    uint32_t r;
    asm("v_cvt_pk_bf16_f32 %0, %1, %2" : "=v"(r) : "v"(lo), "v"(hi));
    return r;
}

__global__ __launch_bounds__(NT, 6)   // 6 waves/SIMD = 24 waves/CU
void k_caps(const float* __restrict__ x, const float* __restrict__ W,
            float* __restrict__ out) {
    extern __shared__ uint32_t u2[];          // [GG][RR][8] packed bf16 pairs
    __shared__ float part[NWAVE][17];         // wave index implies g (wv/6)
    __shared__ float p0s[NWAVE][8][4][GG];    // [wv][lane 2q][j][g]
    __shared__ float wsum[GG][OO];

    const int t = threadIdx.x;
    const int c  = blockIdx.x / (BB / GG);    // c-major: 128 blocks share W-slice
    const int b0 = (blockIdx.x % (BB / GG)) * GG;
    const int wv = t >> 6, l = t & 63;
    const int rg = t >> 3, p = t & 7;         // phase 1: 96 r-rows x 8 lanes

    uint32_t* uA = u2;                        // batch b0
    uint32_t* uB = u2 + (size_t)RR * 8;       // batch b0+1

    // word position within the r-row this lane writes:
    // lane p holds j = p&3, i-half p&1; pos = 2q (rows 0-3) / 2q+1 (rows 4-7)
    const int pos = (p >> 1) + ((p & 1) << 2);
    uint32_t* wrA = uA + (size_t)rg * 8 + pos;
    uint32_t* wrB = uB + (size_t)rg * 8 + pos;

    // ---- Phase 1: u -> LDS (coalesced W reads); fused pass-0 sums ----
    float s00 = 0.f, s01 = 0.f, s02 = 0.f, s03 = 0.f;
    float s10 = 0.f, s11 = 0.f, s12 = 0.f, s13 = 0.f;
#pragma unroll 2
    for (int it = 0; it < RR / 96; ++it) {    // 12 iterations
        const int r = it * 96 + rg;
        // W row (128 floats, 512B contiguous): piece j = floats [j*32+p*4, +4)
        const float* wrow = W + ((size_t)r * CC + c) * (OO * II) + p * 4;
        float4 w0 = *reinterpret_cast<const float4*>(wrow);
        float4 w1 = *reinterpret_cast<const float4*>(wrow + 32);
        float4 w2 = *reinterpret_cast<const float4*>(wrow + 64);
        float4 w3 = *reinterpret_cast<const float4*>(wrow + 96);
        // x: lane loads only its i-half (p&1)
        const float* xp = x + ((size_t)b0 * RR + r) * II + (p & 1) * 4;
        float4 xh0 = *reinterpret_cast<const float4*>(xp);
        float4 xh1 = *reinterpret_cast<const float4*>(xp + (size_t)RR * II);

        // ---- g = 0 ----  d[j] = full dot for o = 4j + (p>>1)
        float d0 = qpadd1(dot4(w0, xh0));
        float d1 = qpadd1(dot4(w1, xh0));
        float d2 = qpadd1(dot4(w2, xh0));
        float d3 = qpadd1(dot4(w3, xh0));
        s00 += d0; s01 += d1; s02 += d2; s03 += d3;
        {
            uint32_t q0 = cvtpk(d0, dppx2f(d0));   // (own, partner)
            uint32_t q1 = cvtpk(d1, dppx2f(d1));
            uint32_t q2 = cvtpk(d2, dppx2f(d2));
            uint32_t q3 = cvtpk(d3, dppx2f(d3));
            uint32_t sa = (p & 2) ? ((p & 1) ? q3 : q2) : ((p & 1) ? q1 : q0);
            wrA[(size_t)it * 768] = sa;       // word (8r+pos): exact 2-way
        }
        // ---- g = 1 ----
        float e0 = qpadd1(dot4(w0, xh1));
        float e1 = qpadd1(dot4(w1, xh1));
        float e2 = qpadd1(dot4(w2, xh1));
        float e3 = qpadd1(dot4(w3, xh1));
        s10 += e0; s11 += e1; s12 += e2; s13 += e3;
        {
            uint32_t q0 = cvtpk(e0, dppx2f(e0));
            uint32_t q1 = cvtpk(e1, dppx2f(e1));
            uint32_t q2 = cvtpk(e2, dppx2f(e2));
            uint32_t q3 = cvtpk(e3, dppx2f(e3));
            uint32_t sa = (p & 2) ? ((p & 1) ? q3 : q2) : ((p & 1) ? q1 : q0);
            wrB[(size_t)it * 768] = sa;
        }
    }
    // reduce pass-0 partials over the 8 r-groups of the wave (masks 8,16,32)
#pragma unroll
    for (int m = 8; m < 64; m <<= 1) {
        s00 += __shfl_xor(s00, m); s01 += __shfl_xor(s01, m);
        s02 += __shfl_xor(s02, m); s03 += __shfl_xor(s03, m);
        s10 += __shfl_xor(s10, m); s11 += __shfl_xor(s11, m);
        s12 += __shfl_xor(s12, m); s13 += __shfl_xor(s13, m);
    }
    if (l < 8) {          // lane l holds o = 4j + (l>>1); dup pairs harmless
        p0s[wv][l][0][0] = s00; p0s[wv][l][1][0] = s01;
        p0s[wv][l][2][0] = s02; p0s[wv][l][3][0] = s03;
        p0s[wv][l][0][1] = s10; p0s[wv][l][1][1] = s11;
        p0s[wv][l][2][1] = s12; p0s[wv][l][3][1] = s13;
    }
    __syncthreads();

    if (t < GG * OO) {   // g = t>>4, o = t&15 (wave 0)
        const int g = t >> 4, o = t & 15;
        float s = 0.f;
#pragma unroll
        for (int w = 0; w < NWAVE; ++w) s += p0s[w][2 * (o & 3)][o >> 2][g];
        s *= (1.0f / RR);                     // softmax(0) = 1/R
        float ss = s * s;                     // squash over 16-lane o-group
        ss += __shfl_xor(ss, 1); ss += __shfl_xor(ss, 2);
        ss += __shfl_xor(ss, 4); ss += __shfl_xor(ss, 8);
        wsum[g][o] = s * (ss / ((1.0f + ss) * sqrtf(ss + 1e-7f)));  // v0
    }
    __syncthreads();

    // ---- Phase 2: passes 1 and 2 from LDS; lane-quad owns one r ----
    const int g2 = wv / 6;                    // waves 0-5: g=0, waves 6-11: g=1
    const int wv6 = wv - g2 * 6;              // wave within the g-half
    const uint32_t* ug = g2 ? uB : uA;
    const int q = l & 3;                      // owns o in {2q,2q+1,2q+8,2q+9}
    const int rl = l >> 2;                    // 0..15
    const int rbase = wv6 * 16 + rl;
    const uint32_t* rp = ug + (size_t)rbase * 8 + 2 * q;   // words 2q,2q+1

    for (int pass = 1; pass < 3; ++pass) {
        const float2v WQA = { wsum[g2][2 * q],     wsum[g2][2 * q + 8] };
        const float2v WQB = { wsum[g2][2 * q + 1], wsum[g2][2 * q + 9] };
        float2v N0 = { 0.f, 0.f }, N1 = { 0.f, 0.f };
        float den = 0.f;

#pragma unroll
        for (int it2 = 0; it2 < 12; ++it2) {
            uint2 pp = *reinterpret_cast<const uint2*>(rp + (size_t)it2 * 768);
            // pp.x = row q (2q lo, 2q+1 hi); pp.y = row q+4 (2q+9 lo, 2q+8 hi)
            float2v P0 = { bflo(pp.x), bfhi(pp.y) };   // (u[2q],   u[2q+8])
            float2v P1 = { bfhi(pp.x), bflo(pp.y) };   // (u[2q+1], u[2q+9])
            float2v lg2 = __builtin_elementwise_fma(P0, WQA, P1 * WQB);
            float lg = lg2.x + lg2.y;
            lg = qpadd1(lg);                  // + lane^1 (quad partial)
            lg = qpadd2(lg);                  // + lane^2: full 16-o logit
            float e = __expf(lg);             // |logit| <~ 40: fp32-safe
            den += e;                         // same-q lanes hold distinct r's
            float2v E2 = { e, e };
            N0 = __builtin_elementwise_fma(E2, P0, N0);
            N1 = __builtin_elementwise_fma(E2, P1, N1);
        }

        float n0 = N0.x, n2 = N0.y, n1 = N1.x, n3 = N1.y;
#pragma unroll
        for (int m = 4; m < 64; m <<= 1) {
            n0 += __shfl_xor(n0, m); n1 += __shfl_xor(n1, m);
            n2 += __shfl_xor(n2, m); n3 += __shfl_xor(n3, m);
            den += __shfl_xor(den, m);
        }
        if (l < 4) {                          // lane l == q
            part[wv][2 * l]     = n0;
            part[wv][2 * l + 1] = n1;
            part[wv][2 * l + 8] = n2;
            part[wv][2 * l + 9] = n3;
            if (l == 0) part[wv][16] = den;   // each r counted exactly once
        }
        __syncthreads();

        if (t < GG * OO) {
            const int g = t >> 4, o = t & 15;
            float nf = 0.f, df = 0.f;
#pragma unroll
            for (int w = 0; w < 6; ++w) {
                nf += part[6 * g + w][o];
                df += part[6 * g + w][16];
            }
            float s = nf / df;
            float ss = s * s;
            ss += __shfl_xor(ss, 1); ss += __shfl_xor(ss, 2);
            ss += __shfl_xor(ss, 4); ss += __shfl_xor(ss, 8);
            float v = s * (ss / ((1.0f + ss) * sqrtf(ss + 1e-7f)));
            if (pass == 2)
                out[((size_t)(b0 + g) * CC + c) * OO + o] = v;
            else
                wsum[g][o] += v;
        }
        __syncthreads();
    }
}

extern "C" void kernel_launch(void* const* d_in, const int* in_sizes, int n_in,
                              void* d_out, int out_size, void* d_ws, size_t ws_size,
                              hipStream_t stream) {
    const float* x = (const float*)d_in[0];  // (B,R,I) fp32
    const float* W = (const float*)d_in[1];  // (R,C,O,I) fp32
    if (n_in >= 2 && in_sizes[0] == RR * CC * OO * II &&
        in_sizes[1] == BB * RR * II) {
        const float* tmp = x; x = W; W = tmp;
    }
    float* out = (float*)d_out;              // (B,1,C,O,1) fp32

    const size_t dyn_lds = (size_t)GG * RR * 8 * 4;   // 73,728 B
    k_caps<<<CC * (BB / GG), NT, dyn_lds, stream>>>(x, W, out);
}

// Round 7
// 105.707 us; speedup vs baseline: 1.3845x; 1.0211x over previous
//
#include <hip/hip_runtime.h>
#include <cstdint>

// CapsuleLayer dynamic routing: B=256, R=1152, C=10, O=16, I=8, 3 iters.
// Round 7: ILP/latency attack (r6 showed bank conflicts were hidden; 43%
// of time is dependency stalls, VGPR=36 = compiler kept nothing in flight).
//  * Phase 2: all 12 ds_read_b64 preloaded into pv[12] ONCE (u2 is
//    identical for both passes) -> pass 2 has ZERO LDS reads; preload
//    issues under the v0 epilogue.
//  * Phase 1: full unroll + explicit 1-ahead prefetch of W/x loads
//    (~60 VALU ops cover ~200cy L2 latency).
//  * Issue diet: dot4 via v_pk_fma_f32 (3 ops vs 4); packing is
//    select-two-then-one-cvtpk: lane selects d[p&3] (own) + d[(p&3)^2]
//    (export for xor2 partner), 1 dpp + 1 cvtpk. Produces EXACTLY the
//    same words/pos as round 6 (rows 4-7 swapped; pos=(p>>1)+((p&1)<<2));
//    reader untouched. exp folded to raw v_exp_f32 by scaling wreg by
//    log2(e) (exp2(x*log2e) == exp(x), same HW unit, same values).
// LDS [g][r][8] words, 73.7KB, 2 blocks/CU, 768 threads.
#define BB 256
#define RR 1152
#define CC 10
#define OO 16
#define II 8
#define NT 768
#define GG 2
#define NWAVE (NT / 64)    // 12
#define LOG2E 1.4426950408889634f

typedef float float2v __attribute__((ext_vector_type(2)));

__device__ __forceinline__ float bflo(uint32_t pk) {
    union { uint32_t i; float f; } a; a.i = pk << 16; return a.f;
}
__device__ __forceinline__ float bfhi(uint32_t pk) {
    union { uint32_t i; float f; } a; a.i = pk & 0xffff0000u; return a.f;
}
// dot4 via packed f32: 2 pk_fma-class ops + 1 hadd
__device__ __forceinline__ float dot4pk(float4 a, float4 b) {
    float2v al = { a.x, a.y }, ah = { a.z, a.w };
    float2v bl = { b.x, b.y }, bh = { b.z, b.w };
    float2v h = __builtin_elementwise_fma(ah, bh, al * bl);
    return h.x + h.y;
}
// v + (value from lane l^1), DPP quad_perm [1,0,3,2] — VALU pipe
__device__ __forceinline__ float qpadd1(float v) {
    int o = __builtin_amdgcn_mov_dpp(__float_as_int(v), 0xB1, 0xF, 0xF, true);
    return v + __int_as_float(o);
}
// v + (value from lane l^2), DPP quad_perm [2,3,0,1]
__device__ __forceinline__ float qpadd2(float v) {
    int o = __builtin_amdgcn_mov_dpp(__float_as_int(v), 0x4E, 0xF, 0xF, true);
    return v + __int_as_float(o);
}
// value from lane l^2 (float), DPP quad_perm [2,3,0,1]
__device__ __forceinline__ float dppx2f(float v) {
    return __int_as_float(__builtin_amdgcn_mov_dpp(__float_as_int(v), 0x4E, 0xF, 0xF, true));
}
// packed bf16 pair from two f32 (hardware RNE), one instruction
__device__ __forceinline__ uint32_t cvtpk(float lo, float hi) {
    uint32_t r;
    asm("v_cvt_pk_bf16_f32 %0, %1, %2" : "=v"(r) : "v"(lo), "v"(hi));
    return r;
}
#if __has_builtin(__builtin_amdgcn_exp2f)
#define EXP2(x) __builtin_amdgcn_exp2f(x)
#else
#define EXP2(x) __expf((x) * 0.6931471805599453f)
#endif

__global__ __launch_bounds__(NT, 6)   // 6 waves/SIMD = 24 waves/CU
void k_caps(const float* __restrict__ x, const float* __restrict__ W,
            float* __restrict__ out) {
    extern __shared__ uint32_t u2[];          // [GG][RR][8] packed bf16 pairs
    __shared__ float part[NWAVE][17];         // wave index implies g (wv/6)
    __shared__ float p0s[NWAVE][8][4][GG];    // [wv][lane 2q][j][g]
    __shared__ float wsum[GG][OO];

    const int t = threadIdx.x;
    const int c  = blockIdx.x / (BB / GG);    // c-major: 128 blocks share W-slice
    const int b0 = (blockIdx.x % (BB / GG)) * GG;
    const int wv = t >> 6, l = t & 63;
    const int rg = t >> 3, p = t & 7;         // phase 1: 96 r-rows x 8 lanes

    uint32_t* uA = u2;                        // batch b0
    uint32_t* uB = u2 + (size_t)RR * 8;       // batch b0+1

    const int pos = (p >> 1) + ((p & 1) << 2);
    uint32_t* wrA = uA + (size_t)rg * 8 + pos;
    uint32_t* wrB = uB + (size_t)rg * 8 + pos;
    const bool pb0 = (p & 1) != 0, pb1 = (p & 2) != 0;

    // ---- Phase 1: u -> LDS; fused pass-0 sums; 1-ahead prefetch ----
    float s00 = 0.f, s01 = 0.f, s02 = 0.f, s03 = 0.f;
    float s10 = 0.f, s11 = 0.f, s12 = 0.f, s13 = 0.f;
    const float* wbase = W + ((size_t)rg * CC + c) * (OO * II) + p * 4;
    const float* xbase = x + ((size_t)b0 * RR + rg) * II + (p & 1) * 4;
    const size_t WSTEP = (size_t)96 * CC * OO * II;   // 122880 floats
    const size_t XSTEP = (size_t)96 * II;             // 768 floats
    float4 cw0 = *reinterpret_cast<const float4*>(wbase);
    float4 cw1 = *reinterpret_cast<const float4*>(wbase + 32);
    float4 cw2 = *reinterpret_cast<const float4*>(wbase + 64);
    float4 cw3 = *reinterpret_cast<const float4*>(wbase + 96);
    float4 cx0 = *reinterpret_cast<const float4*>(xbase);
    float4 cx1 = *reinterpret_cast<const float4*>(xbase + (size_t)RR * II);
#pragma unroll
    for (int it = 0; it < 12; ++it) {
        float4 w0 = cw0, w1 = cw1, w2 = cw2, w3 = cw3;
        float4 xh0 = cx0, xh1 = cx1;
        if (it < 11) {                        // issue next-iter loads first
            const float* nw = wbase + (size_t)(it + 1) * WSTEP;
            cw0 = *reinterpret_cast<const float4*>(nw);
            cw1 = *reinterpret_cast<const float4*>(nw + 32);
            cw2 = *reinterpret_cast<const float4*>(nw + 64);
            cw3 = *reinterpret_cast<const float4*>(nw + 96);
            const float* nx = xbase + (size_t)(it + 1) * XSTEP;
            cx0 = *reinterpret_cast<const float4*>(nx);
            cx1 = *reinterpret_cast<const float4*>(nx + (size_t)RR * II);
        }
        // ---- g = 0 ----
        {
            float d0 = qpadd1(dot4pk(w0, xh0));
            float d1 = qpadd1(dot4pk(w1, xh0));
            float d2 = qpadd1(dot4pk(w2, xh0));
            float d3 = qpadd1(dot4pk(w3, xh0));
            s00 += d0; s01 += d1; s02 += d2; s03 += d3;
            // own j = p&3; export j = (p&3)^2 (for xor2 partner's word)
            float sa = pb1 ? (pb0 ? d3 : d2) : (pb0 ? d1 : d0);
            float sb = pb1 ? (pb0 ? d1 : d0) : (pb0 ? d3 : d2);
            wrA[(size_t)it * 768] = cvtpk(sa, dppx2f(sb));
        }
        // ---- g = 1 ----
        {
            float e0 = qpadd1(dot4pk(w0, xh1));
            float e1 = qpadd1(dot4pk(w1, xh1));
            float e2 = qpadd1(dot4pk(w2, xh1));
            float e3 = qpadd1(dot4pk(w3, xh1));
            s10 += e0; s11 += e1; s12 += e2; s13 += e3;
            float sa = pb1 ? (pb0 ? e3 : e2) : (pb0 ? e1 : e0);
            float sb = pb1 ? (pb0 ? e1 : e0) : (pb0 ? e3 : e2);
            wrB[(size_t)it * 768] = cvtpk(sa, dppx2f(sb));
        }
    }
    // reduce pass-0 partials over the 8 r-groups of the wave (masks 8,16,32)
#pragma unroll
    for (int m = 8; m < 64; m <<= 1) {
        s00 += __shfl_xor(s00, m); s01 += __shfl_xor(s01, m);
        s02 += __shfl_xor(s02, m); s03 += __shfl_xor(s03, m);
        s10 += __shfl_xor(s10, m); s11 += __shfl_xor(s11, m);
        s12 += __shfl_xor(s12, m); s13 += __shfl_xor(s13, m);
    }
    if (l < 8) {          // lane l holds o = 4j + (l>>1); dup pairs harmless
        p0s[wv][l][0][0] = s00; p0s[wv][l][1][0] = s01;
        p0s[wv][l][2][0] = s02; p0s[wv][l][3][0] = s03;
        p0s[wv][l][0][1] = s10; p0s[wv][l][1][1] = s11;
        p0s[wv][l][2][1] = s12; p0s[wv][l][3][1] = s13;
    }
    __syncthreads();

    // ---- Phase 2 mapping + LDS preload (u2 is final; reused for BOTH passes)
    const int g2 = wv / 6;                    // waves 0-5: g=0, waves 6-11: g=1
    const int wv6 = wv - g2 * 6;              // wave within the g-half
    const uint32_t* ug = g2 ? uB : uA;
    const int q = l & 3;                      // owns o in {2q,2q+1,2q+8,2q+9}
    const int rl = l >> 2;                    // 0..15
    const int rbase = wv6 * 16 + rl;
    const uint32_t* rp = ug + (size_t)rbase * 8 + 2 * q;   // words 2q,2q+1

    uint2 pv[12];
#pragma unroll
    for (int it2 = 0; it2 < 12; ++it2)        // hides under v0 epilogue
        pv[it2] = *reinterpret_cast<const uint2*>(rp + (size_t)it2 * 768);

    if (t < GG * OO) {   // g = t>>4, o = t&15 (wave 0)
        const int g = t >> 4, o = t & 15;
        float s = 0.f;
#pragma unroll
        for (int w = 0; w < NWAVE; ++w) s += p0s[w][2 * (o & 3)][o >> 2][g];
        s *= (1.0f / RR);                     // softmax(0) = 1/R
        float ss = s * s;                     // squash over 16-lane o-group
        ss += __shfl_xor(ss, 1); ss += __shfl_xor(ss, 2);
        ss += __shfl_xor(ss, 4); ss += __shfl_xor(ss, 8);
        wsum[g][o] = s * (ss / ((1.0f + ss) * sqrtf(ss + 1e-7f)));  // v0
    }
    __syncthreads();

    // ---- Phase 2: passes 1 and 2 entirely from registers ----
    for (int pass = 1; pass < 3; ++pass) {
        // routing weights pre-scaled by log2(e): exp2(lg) == exp(raw)
        const float2v WQA = { wsum[g2][2 * q] * LOG2E,
                              wsum[g2][2 * q + 8] * LOG2E };
        const float2v WQB = { wsum[g2][2 * q + 1] * LOG2E,
                              wsum[g2][2 * q + 9] * LOG2E };
        float2v N0 = { 0.f, 0.f }, N1 = { 0.f, 0.f };
        float den = 0.f;

#pragma unroll
        for (int it2 = 0; it2 < 12; ++it2) {
            uint2 pp = pv[it2];
            // pp.x = row q (2q lo, 2q+1 hi); pp.y = row q+4 (2q+9 lo, 2q+8 hi)
            float2v P0 = { bflo(pp.x), bfhi(pp.y) };   // (u[2q],   u[2q+8])
            float2v P1 = { bfhi(pp.x), bflo(pp.y) };   // (u[2q+1], u[2q+9])
            float2v lg2 = __builtin_elementwise_fma(P0, WQA, P1 * WQB);
            float lg = lg2.x + lg2.y;
            lg = qpadd1(lg);                  // + lane^1 (quad partial)
            lg = qpadd2(lg);                  // + lane^2: full 16-o logit
            float e = EXP2(lg);               // == exp(raw logit)
            den += e;                         // same-q lanes hold distinct r's
            float2v E2 = { e, e };
            N0 = __builtin_elementwise_fma(E2, P0, N0);
            N1 = __builtin_elementwise_fma(E2, P1, N1);
        }

        float n0 = N0.x, n2 = N0.y, n1 = N1.x, n3 = N1.y;
#pragma unroll
        for (int m = 4; m < 64; m <<= 1) {
            n0 += __shfl_xor(n0, m); n1 += __shfl_xor(n1, m);
            n2 += __shfl_xor(n2, m); n3 += __shfl_xor(n3, m);
            den += __shfl_xor(den, m);
        }
        if (l < 4) {                          // lane l == q
            part[wv][2 * l]     = n0;
            part[wv][2 * l + 1] = n1;
            part[wv][2 * l + 8] = n2;
            part[wv][2 * l + 9] = n3;
            if (l == 0) part[wv][16] = den;   // each r counted exactly once
        }
        __syncthreads();

        if (t < GG * OO) {
            const int g = t >> 4, o = t & 15;
            float nf = 0.f, df = 0.f;
#pragma unroll
            for (int w = 0; w < 6; ++w) {
                nf += part[6 * g + w][o];
                df += part[6 * g + w][16];
            }
            float s = nf / df;
            float ss = s * s;
            ss += __shfl_xor(ss, 1); ss += __shfl_xor(ss, 2);
            ss += __shfl_xor(ss, 4); ss += __shfl_xor(ss, 8);
            float v = s * (ss / ((1.0f + ss) * sqrtf(ss + 1e-7f)));
            if (pass == 2)
                out[((size_t)(b0 + g) * CC + c) * OO + o] = v;
            else
                wsum[g][o] += v;
        }
        __syncthreads();
    }
}

extern "C" void kernel_launch(void* const* d_in, const int* in_sizes, int n_in,
                              void* d_out, int out_size, void* d_ws, size_t ws_size,
                              hipStream_t stream) {
    const float* x = (const float*)d_in[0];  // (B,R,I) fp32
    const float* W = (const float*)d_in[1];  // (R,C,O,I) fp32
    if (n_in >= 2 && in_sizes[0] == RR * CC * OO * II &&
        in_sizes[1] == BB * RR * II) {
        const float* tmp = x; x = W; W = tmp;
    }
    float* out = (float*)d_out;              // (B,1,C,O,1) fp32

    const size_t dyn_lds = (size_t)GG * RR * 8 * 4;   // 73,728 B
    k_caps<<<CC * (BB / GG), NT, dyn_lds, stream>>>(x, W, out);
}